// Round 6
// baseline (638.214 us; speedup 1.0000x reference)
//
#include <hip/hip_runtime.h>
#include <math.h>

#define N_NODES 50000
#define F_DIM   128
#define E_EDGES 800000
#define NPB     40    // nodes per fused block (1250 blocks exactly)
#define CAP     64    // bucket capacity per node (Poisson(16): P(deg>64) negligible)
#define APAD    132   // padded row stride (floats): keeps GEMM b128 reads conflict-free

// ---------------- JAX threefry (partitionable path, o0^o1) — verified r2 ----------------
__device__ __forceinline__ unsigned rotl32(unsigned x, int d) {
  return (x << d) | (x >> (32 - d));
}

__device__ __forceinline__ void tf2x32(unsigned k0, unsigned k1,
                                       unsigned c0, unsigned c1,
                                       unsigned &o0, unsigned &o1) {
  unsigned ks2 = k0 ^ k1 ^ 0x1BD11BDAu;
  unsigned x0 = c0 + k0, x1 = c1 + k1;
#define TF_R(a) { x0 += x1; x1 = rotl32(x1, a); x1 ^= x0; }
  TF_R(13) TF_R(15) TF_R(26) TF_R(6)   x0 += k1;  x1 += ks2 + 1u;
  TF_R(17) TF_R(29) TF_R(16) TF_R(24)  x0 += ks2; x1 += k0 + 2u;
  TF_R(13) TF_R(15) TF_R(26) TF_R(6)   x0 += k0;  x1 += k1 + 3u;
  TF_R(17) TF_R(29) TF_R(16) TF_R(24)  x0 += k1;  x1 += ks2 + 4u;
  TF_R(13) TF_R(15) TF_R(26) TF_R(6)   x0 += ks2; x1 += k0 + 5u;
#undef TF_R
  o0 = x0; o1 = x1;
}

__device__ __forceinline__ bool keep_elem(unsigned j) {
  unsigned o0, o1;
  tf2x32(0u, 42u, 0u, j, o0, o1);
  unsigned bits = o0 ^ o1;
  float uf = __uint_as_float((bits >> 9) | 0x3f800000u) - 1.0f;
  return uf < 0.7f;
}

// ---------------- bucket build ----------------
__global__ __launch_bounds__(256) void fill_bucket(const int* __restrict__ src,
                                                   const int* __restrict__ dst,
                                                   int* __restrict__ cursor,
                                                   int* __restrict__ bucket) {
  int e = blockIdx.x * 256 + threadIdx.x;   // grid covers exactly E_EDGES
  int d = dst[e];
  int pos = atomicAdd(&cursor[d], 1);
  if (pos < CAP) bucket[d * CAP + pos] = src[e];
}

// -------- fused: edge-parallel gather-mean (ds_add_f32) + dual GEMM + epilogue --------
// Gather: block's edges compacted into LDS list; 8 groups of 32 lanes sweep it; per edge
//   lane li loads cols {li,li+32,li+64,li+96} (4 coalesced dwords) and ds_add's them into
//   A[1][ln] — banks (4*ln+li)%32 distinct per lane => conflict-free; all loads independent.
// GEMM: h=t>>7 (0:self/A[0], 1:neigh/A[1]), rg=(t>>4)&7 -> 5 rows, cg=t&15 -> 8 cols.
__global__ __launch_bounds__(256) void fused_kernel(
    const float* __restrict__ x,
    const int* __restrict__ cursor, const int* __restrict__ bucket,
    const float* __restrict__ Wself, const float* __restrict__ Wneigh,
    const float* __restrict__ bias, float* __restrict__ out) {
  __shared__ __align__(16) float A[2][NPB][APAD];   // 42.2 KB
  __shared__ int   flat[NPB * CAP];                 // 10 KB packed (ln<<16)|src
  __shared__ float rowss[2][NPB];
  __shared__ int   degs[NPB];
  __shared__ int   off[NPB + 1];
  __shared__ float invd[NPB];

  const int t = threadIdx.x;
  const int row0 = blockIdx.x * NPB;

  // ---- stage x rows (1280 float4, coalesced), zero A[1], load degrees ----
#pragma unroll
  for (int k = 0; k < 5; ++k) {
    int q = k * 256 + t;
    int row = q >> 5, f4 = q & 31;
    ((float4*)A[0][row])[f4] = ((const float4*)(x + (size_t)(row0 + row) * F_DIM))[f4];
  }
  {
    float4 z; z.x = z.y = z.z = z.w = 0.0f;
    float4* A1 = (float4*)&A[1][0][0];              // 40*132 floats = 1320 float4
#pragma unroll
    for (int k = 0; k < 6; ++k) {
      int q = k * 256 + t;
      if (q < (NPB * APAD) / 4) A1[q] = z;
    }
  }
  if (t < NPB) {
    int d = cursor[row0 + t];
    degs[t] = d < CAP ? d : CAP;
  }
  __syncthreads();

  // ---- wave 0: exclusive prefix over degs + reciprocal degrees ----
  if (t < 64) {
    int v = (t < NPB) ? degs[t] : 0;
    int own = v;
#pragma unroll
    for (int d = 1; d < 64; d <<= 1) {
      int u = __shfl_up(v, d, 64);
      if (t >= d) v += u;
    }
    if (t < NPB) {
      off[t] = v - own;
      invd[t] = 1.0f / (float)(own > 1 ? own : 1);
    }
    if (t == NPB - 1) off[NPB] = v;                 // total edge count
  }
  __syncthreads();

  // ---- compact bucket slots into flat edge list (coalesced bucket reads) ----
#pragma unroll
  for (int k = 0; k < 10; ++k) {                    // NPB*CAP = 2560 slots
    int s = k * 256 + t;
    int ln = s >> 6, j = s & (CAP - 1);
    if (j < degs[ln]) {
      int sv = bucket[(size_t)row0 * CAP + s];
      flat[off[ln] + j] = (ln << 16) | sv;          // src < 50000 < 2^16
    }
  }
  __syncthreads();

  // ---- gather: edge-parallel, all loads independent, conflict-free ds_add ----
  {
    const int gi = t >> 5, li = t & 31;
    const int cnt = off[NPB];
    for (int i = gi; i < cnt; i += 8) {
      int p = flat[i];
      int ln = p >> 16, sidx = p & 0xFFFF;
      const float* xr = x + (size_t)sidx * F_DIM + li;
      float v0 = xr[0], v1 = xr[32], v2 = xr[64], v3 = xr[96];
      atomicAdd(&A[1][ln][li +  0], v0);
      atomicAdd(&A[1][ln][li + 32], v1);
      atomicAdd(&A[1][ln][li + 64], v2);
      atomicAdd(&A[1][ln][li + 96], v3);
    }
  }
  __syncthreads();

  // ---- sums -> means ----
#pragma unroll
  for (int k = 0; k < 5; ++k) {                     // 40 rows * 32 float4
    int q = k * 256 + t;
    int ln = q >> 5, f4 = q & 31;
    float4 v = ((float4*)A[1][ln])[f4];
    float s = invd[ln];
    v.x *= s; v.y *= s; v.z *= s; v.w *= s;
    ((float4*)A[1][ln])[f4] = v;
  }
  __syncthreads();

  // ---- GEMM phase ----
  const int h = t >> 7, rg = (t >> 4) & 7, cg = t & 15;
  const float* W = h ? Wneigh : Wself;

  float acc[5][8];
#pragma unroll
  for (int i = 0; i < 5; ++i)
#pragma unroll
    for (int c = 0; c < 8; ++c) acc[i][c] = 0.0f;

  for (int kc = 0; kc < 16; ++kc) {                 // 8 k-values per chunk
    float4 w0[8], w1[8];
#pragma unroll
    for (int f = 0; f < 8; ++f) {
      const float* wr = W + (size_t)(kc * 8 + f) * 128 + cg * 8;
      w0[f] = *(const float4*)wr;
      w1[f] = *(const float4*)(wr + 4);
    }
#pragma unroll
    for (int i = 0; i < 5; ++i) {
      const float4* Ap = (const float4*)A[h][rg * 5 + i];
      float4 a0 = Ap[kc * 2 + 0];
      float4 a1 = Ap[kc * 2 + 1];
#define FMA8(av, f) \
      acc[i][0] = fmaf(av, w0[f].x, acc[i][0]); \
      acc[i][1] = fmaf(av, w0[f].y, acc[i][1]); \
      acc[i][2] = fmaf(av, w0[f].z, acc[i][2]); \
      acc[i][3] = fmaf(av, w0[f].w, acc[i][3]); \
      acc[i][4] = fmaf(av, w1[f].x, acc[i][4]); \
      acc[i][5] = fmaf(av, w1[f].y, acc[i][5]); \
      acc[i][6] = fmaf(av, w1[f].z, acc[i][6]); \
      acc[i][7] = fmaf(av, w1[f].w, acc[i][7]);
      FMA8(a0.x, 0) FMA8(a0.y, 1) FMA8(a0.z, 2) FMA8(a0.w, 3)
      FMA8(a1.x, 4) FMA8(a1.y, 5) FMA8(a1.z, 6) FMA8(a1.w, 7)
#undef FMA8
    }
  }

  // ---- epilogue: +bias, ELU, dropout, row sum-of-squares, l2norm, store ----
  float4 b0 = ((const float4*)bias)[h * 32 + cg * 2];
  float4 b1 = ((const float4*)bias)[h * 32 + cg * 2 + 1];
  float bb[8] = {b0.x, b0.y, b0.z, b0.w, b1.x, b1.y, b1.z, b1.w};

  float ss[5];
#pragma unroll
  for (int i = 0; i < 5; ++i) {
    unsigned n = row0 + rg * 5 + i;
    unsigned colbase = h * 128u + (unsigned)cg * 8u;
    ss[i] = 0.0f;
#pragma unroll
    for (int c = 0; c < 8; ++c) {
      float val = acc[i][c] + bb[c];
      val = (val > 0.0f) ? val : expm1f(val);
      val = keep_elem(n * 256u + colbase + c) ? val * (1.0f / 0.7f) : 0.0f;
      acc[i][c] = val;
      ss[i] = fmaf(val, val, ss[i]);
    }
  }
#pragma unroll
  for (int d = 1; d < 16; d <<= 1)
#pragma unroll
    for (int i = 0; i < 5; ++i) ss[i] += __shfl_xor(ss[i], d, 16);
  if (cg == 0) {
#pragma unroll
    for (int i = 0; i < 5; ++i) rowss[h][rg * 5 + i] = ss[i];
  }
  __syncthreads();

#pragma unroll
  for (int i = 0; i < 5; ++i) {
    int lrow = rg * 5 + i;
    float scale = rsqrtf(fmaxf(rowss[0][lrow] + rowss[1][lrow], 1e-12f));
    size_t n = (size_t)(row0 + lrow);
    float* op = out + n * 256 + h * 128 + cg * 8;
    float4 o0, o1;
    o0.x = acc[i][0] * scale; o0.y = acc[i][1] * scale;
    o0.z = acc[i][2] * scale; o0.w = acc[i][3] * scale;
    o1.x = acc[i][4] * scale; o1.y = acc[i][5] * scale;
    o1.z = acc[i][6] * scale; o1.w = acc[i][7] * scale;
    *(float4*)op = o0;
    *(float4*)(op + 4) = o1;
  }
}

extern "C" void kernel_launch(void* const* d_in, const int* in_sizes, int n_in,
                              void* d_out, int out_size, void* d_ws, size_t ws_size,
                              hipStream_t stream) {
  const float* x      = (const float*)d_in[0];
  const float* Wself  = (const float*)d_in[1];
  const float* Wneigh = (const float*)d_in[2];
  const float* bias   = (const float*)d_in[3];
  const int*   src    = (const int*)d_in[4];   // jnp.int64 degrades to int32 (x64 off)
  const int*   dst    = (const int*)d_in[5];
  float* out = (float*)d_out;

  char* p = (char*)d_ws;
  int* cursor = (int*)p;                       // 200,000 B
  int* bucket = (int*)(p + 200704);            // 12,800,000 B (end ~13 MB)

  hipMemsetAsync(cursor, 0, 200000, stream);
  fill_bucket <<<E_EDGES / 256, 256, 0, stream>>>(src, dst, cursor, bucket);
  fused_kernel<<<N_NODES / NPB, 256, 0, stream>>>(x, cursor, bucket,
                                                  Wself, Wneigh, bias, out);
}

// Round 7
// 190.298 us; speedup vs baseline: 3.3538x; 3.3538x over previous
//
#include <hip/hip_runtime.h>
#include <math.h>

#define N_NODES 50000
#define F_DIM   128
#define E_EDGES 800000
#define NPB     40    // nodes per fused block (1250 blocks exactly)
#define CAP     64    // bucket capacity per node (Poisson(16): P(deg>64) negligible)
#define APAD    132   // padded row stride (floats): keeps GEMM b128 reads conflict-free

// ---------------- JAX threefry (partitionable path, o0^o1) — verified r2 ----------------
__device__ __forceinline__ unsigned rotl32(unsigned x, int d) {
  return (x << d) | (x >> (32 - d));
}

__device__ __forceinline__ void tf2x32(unsigned k0, unsigned k1,
                                       unsigned c0, unsigned c1,
                                       unsigned &o0, unsigned &o1) {
  unsigned ks2 = k0 ^ k1 ^ 0x1BD11BDAu;
  unsigned x0 = c0 + k0, x1 = c1 + k1;
#define TF_R(a) { x0 += x1; x1 = rotl32(x1, a); x1 ^= x0; }
  TF_R(13) TF_R(15) TF_R(26) TF_R(6)   x0 += k1;  x1 += ks2 + 1u;
  TF_R(17) TF_R(29) TF_R(16) TF_R(24)  x0 += ks2; x1 += k0 + 2u;
  TF_R(13) TF_R(15) TF_R(26) TF_R(6)   x0 += k0;  x1 += k1 + 3u;
  TF_R(17) TF_R(29) TF_R(16) TF_R(24)  x0 += k1;  x1 += ks2 + 4u;
  TF_R(13) TF_R(15) TF_R(26) TF_R(6)   x0 += ks2; x1 += k0 + 5u;
#undef TF_R
  o0 = x0; o1 = x1;
}

__device__ __forceinline__ bool keep_elem(unsigned j) {
  unsigned o0, o1;
  tf2x32(0u, 42u, 0u, j, o0, o1);
  unsigned bits = o0 ^ o1;
  float uf = __uint_as_float((bits >> 9) | 0x3f800000u) - 1.0f;
  return uf < 0.7f;
}

// ---------------- bucket build ----------------
__global__ __launch_bounds__(256) void fill_bucket(const int* __restrict__ src,
                                                   const int* __restrict__ dst,
                                                   int* __restrict__ cursor,
                                                   int* __restrict__ bucket) {
  int e = blockIdx.x * 256 + threadIdx.x;   // grid covers exactly E_EDGES
  int d = dst[e];
  int pos = atomicAdd(&cursor[d], 1);
  if (pos < CAP) bucket[d * CAP + pos] = src[e];
}

// -------- fused: gather-mean (reg-accum, node-per-group) + dual GEMM + epilogue --------
// Gather: 8 groups of 32 lanes; group g owns nodes g, g+8, ..., g+32 (5 each).
//   Per node: edge list staged as ints inside A[1][ln] (consumed before the float row
//   overwrites it); 4 edges in flight per round (independent float4 loads), row
//   accumulated in 4 VGPRs/lane, mean folded into the single LDS write. No atomics.
// GEMM: h=t>>7 (0:self/A[0], 1:neigh/A[1]), rg=(t>>4)&7 -> 5 rows, cg=t&15 -> 8 cols.
__global__ __launch_bounds__(256) void fused_kernel(
    const float* __restrict__ x,
    const int* __restrict__ cursor, const int* __restrict__ bucket,
    const float* __restrict__ Wself, const float* __restrict__ Wneigh,
    const float* __restrict__ bias, float* __restrict__ out) {
  __shared__ __align__(16) float A[2][NPB][APAD];   // 42.2 KB
  __shared__ float rowss[2][NPB];
  __shared__ int   degs[NPB];
  __shared__ float invd[NPB];

  const int t = threadIdx.x;
  const int row0 = blockIdx.x * NPB;

  // ---- stage x rows (1280 float4, coalesced) ----
#pragma unroll
  for (int k = 0; k < 5; ++k) {
    int q = k * 256 + t;
    int row = q >> 5, f4 = q & 31;
    ((float4*)A[0][row])[f4] = ((const float4*)(x + (size_t)(row0 + row) * F_DIM))[f4];
  }
  // ---- stage edge lists into A[1] rows as ints (640 int4, coalesced) ----
  {
    const int4* b4 = (const int4*)(bucket + (size_t)row0 * CAP);
#pragma unroll
    for (int k = 0; k < 3; ++k) {
      int s = k * 256 + t;                   // int4 slot: ln = s>>4, ints 4(s&15)..
      if (s < (NPB * CAP) / 4) {
        int ln = s >> 4;
        ((int4*)A[1][ln])[s & 15] = b4[s];
      }
    }
  }
  if (t < NPB) {
    int d = cursor[row0 + t];
    d = d < CAP ? d : CAP;
    degs[t] = d;
    invd[t] = 1.0f / (float)(d > 1 ? d : 1);
  }
  __syncthreads();

  // ---- gather: group g -> nodes g, g+8, ..., 4 independent loads in flight ----
  {
    const int g = t >> 5, li = t & 31;
    const float4* x4 = (const float4*)x;
    for (int ln = g; ln < NPB; ln += 8) {
      const int deg = degs[ln];
      const int* ep = (const int*)A[1][ln];  // this node's staged edge list
      float ax = 0.f, ay = 0.f, az = 0.f, aw = 0.f;
      int j = 0;
      for (; j + 4 <= deg; j += 4) {
        int4 e = ((const int4*)ep)[j >> 2];  // broadcast LDS read
        float4 v0 = x4[(size_t)e.x * 32 + li];
        float4 v1 = x4[(size_t)e.y * 32 + li];
        float4 v2 = x4[(size_t)e.z * 32 + li];
        float4 v3 = x4[(size_t)e.w * 32 + li];
        ax += v0.x; ay += v0.y; az += v0.z; aw += v0.w;
        ax += v1.x; ay += v1.y; az += v1.z; aw += v1.w;
        ax += v2.x; ay += v2.y; az += v2.z; aw += v2.w;
        ax += v3.x; ay += v3.y; az += v3.z; aw += v3.w;
      }
      for (; j < deg; ++j) {
        int e0 = ep[j];
        float4 v = x4[(size_t)e0 * 32 + li];
        ax += v.x; ay += v.y; az += v.z; aw += v.w;
      }
      float s = invd[ln];
      float4 r; r.x = ax * s; r.y = ay * s; r.z = az * s; r.w = aw * s;
      ((float4*)A[1][ln])[li] = r;           // overwrites own (consumed) edge list
    }
  }
  __syncthreads();

  // ---- GEMM phase (round-5 verbatim) ----
  const int h = t >> 7, rg = (t >> 4) & 7, cg = t & 15;
  const float* W = h ? Wneigh : Wself;

  float acc[5][8];
#pragma unroll
  for (int i = 0; i < 5; ++i)
#pragma unroll
    for (int c = 0; c < 8; ++c) acc[i][c] = 0.0f;

  for (int kc = 0; kc < 16; ++kc) {          // 8 k-values per chunk
    float4 w0[8], w1[8];
#pragma unroll
    for (int f = 0; f < 8; ++f) {
      const float* wr = W + (size_t)(kc * 8 + f) * 128 + cg * 8;
      w0[f] = *(const float4*)wr;
      w1[f] = *(const float4*)(wr + 4);
    }
#pragma unroll
    for (int i = 0; i < 5; ++i) {
      const float4* Ap = (const float4*)A[h][rg * 5 + i];
      float4 a0 = Ap[kc * 2 + 0];
      float4 a1 = Ap[kc * 2 + 1];
#define FMA8(av, f) \
      acc[i][0] = fmaf(av, w0[f].x, acc[i][0]); \
      acc[i][1] = fmaf(av, w0[f].y, acc[i][1]); \
      acc[i][2] = fmaf(av, w0[f].z, acc[i][2]); \
      acc[i][3] = fmaf(av, w0[f].w, acc[i][3]); \
      acc[i][4] = fmaf(av, w1[f].x, acc[i][4]); \
      acc[i][5] = fmaf(av, w1[f].y, acc[i][5]); \
      acc[i][6] = fmaf(av, w1[f].z, acc[i][6]); \
      acc[i][7] = fmaf(av, w1[f].w, acc[i][7]);
      FMA8(a0.x, 0) FMA8(a0.y, 1) FMA8(a0.z, 2) FMA8(a0.w, 3)
      FMA8(a1.x, 4) FMA8(a1.y, 5) FMA8(a1.z, 6) FMA8(a1.w, 7)
#undef FMA8
    }
  }

  // ---- epilogue: +bias, ELU, dropout, row sum-of-squares, l2norm, store ----
  float4 b0 = ((const float4*)bias)[h * 32 + cg * 2];
  float4 b1 = ((const float4*)bias)[h * 32 + cg * 2 + 1];
  float bb[8] = {b0.x, b0.y, b0.z, b0.w, b1.x, b1.y, b1.z, b1.w};

  float ss[5];
#pragma unroll
  for (int i = 0; i < 5; ++i) {
    unsigned n = row0 + rg * 5 + i;
    unsigned colbase = h * 128u + (unsigned)cg * 8u;
    ss[i] = 0.0f;
#pragma unroll
    for (int c = 0; c < 8; ++c) {
      float val = acc[i][c] + bb[c];
      val = (val > 0.0f) ? val : expm1f(val);
      val = keep_elem(n * 256u + colbase + c) ? val * (1.0f / 0.7f) : 0.0f;
      acc[i][c] = val;
      ss[i] = fmaf(val, val, ss[i]);
    }
  }
#pragma unroll
  for (int d = 1; d < 16; d <<= 1)
#pragma unroll
    for (int i = 0; i < 5; ++i) ss[i] += __shfl_xor(ss[i], d, 16);
  if (cg == 0) {
#pragma unroll
    for (int i = 0; i < 5; ++i) rowss[h][rg * 5 + i] = ss[i];
  }
  __syncthreads();

#pragma unroll
  for (int i = 0; i < 5; ++i) {
    int lrow = rg * 5 + i;
    float scale = rsqrtf(fmaxf(rowss[0][lrow] + rowss[1][lrow], 1e-12f));
    size_t n = (size_t)(row0 + lrow);
    float* op = out + n * 256 + h * 128 + cg * 8;
    float4 o0, o1;
    o0.x = acc[i][0] * scale; o0.y = acc[i][1] * scale;
    o0.z = acc[i][2] * scale; o0.w = acc[i][3] * scale;
    o1.x = acc[i][4] * scale; o1.y = acc[i][5] * scale;
    o1.z = acc[i][6] * scale; o1.w = acc[i][7] * scale;
    *(float4*)op = o0;
    *(float4*)(op + 4) = o1;
  }
}

extern "C" void kernel_launch(void* const* d_in, const int* in_sizes, int n_in,
                              void* d_out, int out_size, void* d_ws, size_t ws_size,
                              hipStream_t stream) {
  const float* x      = (const float*)d_in[0];
  const float* Wself  = (const float*)d_in[1];
  const float* Wneigh = (const float*)d_in[2];
  const float* bias   = (const float*)d_in[3];
  const int*   src    = (const int*)d_in[4];   // jnp.int64 degrades to int32 (x64 off)
  const int*   dst    = (const int*)d_in[5];
  float* out = (float*)d_out;

  char* p = (char*)d_ws;
  int* cursor = (int*)p;                       // 200,000 B
  int* bucket = (int*)(p + 200704);            // 12,800,000 B (end ~13 MB)

  hipMemsetAsync(cursor, 0, 200000, stream);
  fill_bucket <<<E_EDGES / 256, 256, 0, stream>>>(src, dst, cursor, bucket);
  fused_kernel<<<N_NODES / NPB, 256, 0, stream>>>(x, cursor, bucket,
                                                  Wself, Wneigh, bias, out);
}

// Round 8
// 183.546 us; speedup vs baseline: 3.4771x; 1.0368x over previous
//
#include <hip/hip_runtime.h>
#include <hip/hip_fp16.h>
#include <math.h>

#define N_NODES 50000
#define F_DIM   128
#define E_EDGES 800000
#define NPB     40    // nodes per fused block (1250 blocks exactly)
#define CAP     64    // bucket capacity per node (Poisson(16): P(deg>64) negligible)
#define APAD    132   // padded row stride (floats): keeps GEMM b128 reads conflict-free

// ---------------- JAX threefry (partitionable path, o0^o1) — verified r2 ----------------
__device__ __forceinline__ unsigned rotl32(unsigned x, int d) {
  return (x << d) | (x >> (32 - d));
}

__device__ __forceinline__ void tf2x32(unsigned k0, unsigned k1,
                                       unsigned c0, unsigned c1,
                                       unsigned &o0, unsigned &o1) {
  unsigned ks2 = k0 ^ k1 ^ 0x1BD11BDAu;
  unsigned x0 = c0 + k0, x1 = c1 + k1;
#define TF_R(a) { x0 += x1; x1 = rotl32(x1, a); x1 ^= x0; }
  TF_R(13) TF_R(15) TF_R(26) TF_R(6)   x0 += k1;  x1 += ks2 + 1u;
  TF_R(17) TF_R(29) TF_R(16) TF_R(24)  x0 += ks2; x1 += k0 + 2u;
  TF_R(13) TF_R(15) TF_R(26) TF_R(6)   x0 += k0;  x1 += k1 + 3u;
  TF_R(17) TF_R(29) TF_R(16) TF_R(24)  x0 += k1;  x1 += ks2 + 4u;
  TF_R(13) TF_R(15) TF_R(26) TF_R(6)   x0 += ks2; x1 += k0 + 5u;
#undef TF_R
  o0 = x0; o1 = x1;
}

__device__ __forceinline__ bool keep_elem(unsigned j) {
  unsigned o0, o1;
  tf2x32(0u, 42u, 0u, j, o0, o1);
  unsigned bits = o0 ^ o1;
  float uf = __uint_as_float((bits >> 9) | 0x3f800000u) - 1.0f;
  return uf < 0.7f;
}

// ---------------- pack x -> fp16 (halves gather traffic) ----------------
__global__ __launch_bounds__(256) void pack_x(const float* __restrict__ x,
                                              __half* __restrict__ xh) {
  int i = blockIdx.x * 256 + threadIdx.x;        // one float4 -> one half4 (8B)
  float4 v = ((const float4*)x)[i];              // grid covers 1.6M float4 exactly
  __half2 h01 = __floats2half2_rn(v.x, v.y);
  __half2 h23 = __floats2half2_rn(v.z, v.w);
  float2 o;
  o.x = __uint_as_float(*(const unsigned*)&h01);
  o.y = __uint_as_float(*(const unsigned*)&h23);
  ((float2*)xh)[i] = o;
}

// ---------------- bucket build ----------------
__global__ __launch_bounds__(256) void fill_bucket(const int* __restrict__ src,
                                                   const int* __restrict__ dst,
                                                   int* __restrict__ cursor,
                                                   int* __restrict__ bucket) {
  int e = blockIdx.x * 256 + threadIdx.x;   // grid covers exactly E_EDGES
  int d = dst[e];
  int pos = atomicAdd(&cursor[d], 1);
  if (pos < CAP) bucket[d * CAP + pos] = src[e];
}

// -------- fused: fp16 gather-mean (reg-accum, 8-edge ILP) + dual GEMM + epilogue --------
// Gather: 8 groups of 32 lanes; group g owns nodes g, g+8, ... (5 each). Edge lists staged
//   as ints inside A[1][ln] (consumed in-wave before the float row overwrites it). Per
//   round: 8 independent 8B fp16 loads in flight; accumulate f32 in 4 VGPRs/lane.
// GEMM: h=t>>7 (0:self/A[0], 1:neigh/A[1]), rg=(t>>4)&7 -> 5 rows, cg=t&15 -> 8 cols.
__global__ __launch_bounds__(256) void fused_kernel(
    const float* __restrict__ x, const __half* __restrict__ xh,
    const int* __restrict__ cursor, const int* __restrict__ bucket,
    const float* __restrict__ Wself, const float* __restrict__ Wneigh,
    const float* __restrict__ bias, float* __restrict__ out) {
  __shared__ __align__(16) float A[2][NPB][APAD];   // 42.2 KB
  __shared__ float rowss[2][NPB];
  __shared__ int   degs[NPB];
  __shared__ float invd[NPB];

  const int t = threadIdx.x;
  const int row0 = blockIdx.x * NPB;

  // ---- stage x rows (1280 float4, coalesced) ----
#pragma unroll
  for (int k = 0; k < 5; ++k) {
    int q = k * 256 + t;
    int row = q >> 5, f4 = q & 31;
    ((float4*)A[0][row])[f4] = ((const float4*)(x + (size_t)(row0 + row) * F_DIM))[f4];
  }
  // ---- stage edge lists into A[1] rows as ints (640 int4, coalesced) ----
  {
    const int4* b4 = (const int4*)(bucket + (size_t)row0 * CAP);
#pragma unroll
    for (int k = 0; k < 3; ++k) {
      int s = k * 256 + t;                   // int4 slot: ln = s>>4
      if (s < (NPB * CAP) / 4) {
        int ln = s >> 4;
        ((int4*)A[1][ln])[s & 15] = b4[s];
      }
    }
  }
  if (t < NPB) {
    int d = cursor[row0 + t];
    d = d < CAP ? d : CAP;
    degs[t] = d;
    invd[t] = 1.0f / (float)(d > 1 ? d : 1);
  }
  __syncthreads();

  // ---- gather: fp16 rows, 8 independent loads in flight ----
  {
    const int g = t >> 5, li = t & 31;
    const float2* xr = (const float2*)xh;    // 8B granules; row stride = 32
#define ACCH(u) { __half2 h01 = *(const __half2*)&(u).x; \
                  __half2 h23 = *(const __half2*)&(u).y; \
                  float2 f01 = __half22float2(h01); \
                  float2 f23 = __half22float2(h23); \
                  ax += f01.x; ay += f01.y; az += f23.x; aw += f23.y; }
    for (int ln = g; ln < NPB; ln += 8) {
      const int deg = degs[ln];
      const int* ep = (const int*)A[1][ln];  // this node's staged edge list
      float ax = 0.f, ay = 0.f, az = 0.f, aw = 0.f;
      int j = 0;
      for (; j + 8 <= deg; j += 8) {
        int4 e0 = ((const int4*)ep)[(j >> 2) + 0];
        int4 e1 = ((const int4*)ep)[(j >> 2) + 1];
        float2 u0 = xr[(size_t)e0.x * 32 + li];
        float2 u1 = xr[(size_t)e0.y * 32 + li];
        float2 u2 = xr[(size_t)e0.z * 32 + li];
        float2 u3 = xr[(size_t)e0.w * 32 + li];
        float2 u4 = xr[(size_t)e1.x * 32 + li];
        float2 u5 = xr[(size_t)e1.y * 32 + li];
        float2 u6 = xr[(size_t)e1.z * 32 + li];
        float2 u7 = xr[(size_t)e1.w * 32 + li];
        ACCH(u0) ACCH(u1) ACCH(u2) ACCH(u3)
        ACCH(u4) ACCH(u5) ACCH(u6) ACCH(u7)
      }
      if (j + 4 <= deg) {
        int4 e0 = ((const int4*)ep)[j >> 2];
        float2 u0 = xr[(size_t)e0.x * 32 + li];
        float2 u1 = xr[(size_t)e0.y * 32 + li];
        float2 u2 = xr[(size_t)e0.z * 32 + li];
        float2 u3 = xr[(size_t)e0.w * 32 + li];
        ACCH(u0) ACCH(u1) ACCH(u2) ACCH(u3)
        j += 4;
      }
      for (; j < deg; ++j) {
        int e0 = ep[j];
        float2 u0 = xr[(size_t)e0 * 32 + li];
        ACCH(u0)
      }
      float s = invd[ln];
      float4 r; r.x = ax * s; r.y = ay * s; r.z = az * s; r.w = aw * s;
      ((float4*)A[1][ln])[li] = r;           // overwrites own (consumed) edge list
    }
#undef ACCH
  }
  __syncthreads();

  // ---- GEMM phase (round-5 verbatim) ----
  const int h = t >> 7, rg = (t >> 4) & 7, cg = t & 15;
  const float* W = h ? Wneigh : Wself;

  float acc[5][8];
#pragma unroll
  for (int i = 0; i < 5; ++i)
#pragma unroll
    for (int c = 0; c < 8; ++c) acc[i][c] = 0.0f;

  for (int kc = 0; kc < 16; ++kc) {          // 8 k-values per chunk
    float4 w0[8], w1[8];
#pragma unroll
    for (int f = 0; f < 8; ++f) {
      const float* wr = W + (size_t)(kc * 8 + f) * 128 + cg * 8;
      w0[f] = *(const float4*)wr;
      w1[f] = *(const float4*)(wr + 4);
    }
#pragma unroll
    for (int i = 0; i < 5; ++i) {
      const float4* Ap = (const float4*)A[h][rg * 5 + i];
      float4 a0 = Ap[kc * 2 + 0];
      float4 a1 = Ap[kc * 2 + 1];
#define FMA8(av, f) \
      acc[i][0] = fmaf(av, w0[f].x, acc[i][0]); \
      acc[i][1] = fmaf(av, w0[f].y, acc[i][1]); \
      acc[i][2] = fmaf(av, w0[f].z, acc[i][2]); \
      acc[i][3] = fmaf(av, w0[f].w, acc[i][3]); \
      acc[i][4] = fmaf(av, w1[f].x, acc[i][4]); \
      acc[i][5] = fmaf(av, w1[f].y, acc[i][5]); \
      acc[i][6] = fmaf(av, w1[f].z, acc[i][6]); \
      acc[i][7] = fmaf(av, w1[f].w, acc[i][7]);
      FMA8(a0.x, 0) FMA8(a0.y, 1) FMA8(a0.z, 2) FMA8(a0.w, 3)
      FMA8(a1.x, 4) FMA8(a1.y, 5) FMA8(a1.z, 6) FMA8(a1.w, 7)
#undef FMA8
    }
  }

  // ---- epilogue: +bias, ELU, dropout, row sum-of-squares, l2norm, store ----
  float4 b0 = ((const float4*)bias)[h * 32 + cg * 2];
  float4 b1 = ((const float4*)bias)[h * 32 + cg * 2 + 1];
  float bb[8] = {b0.x, b0.y, b0.z, b0.w, b1.x, b1.y, b1.z, b1.w};

  float ss[5];
#pragma unroll
  for (int i = 0; i < 5; ++i) {
    unsigned n = row0 + rg * 5 + i;
    unsigned colbase = h * 128u + (unsigned)cg * 8u;
    ss[i] = 0.0f;
#pragma unroll
    for (int c = 0; c < 8; ++c) {
      float val = acc[i][c] + bb[c];
      val = (val > 0.0f) ? val : expm1f(val);
      val = keep_elem(n * 256u + colbase + c) ? val * (1.0f / 0.7f) : 0.0f;
      acc[i][c] = val;
      ss[i] = fmaf(val, val, ss[i]);
    }
  }
#pragma unroll
  for (int d = 1; d < 16; d <<= 1)
#pragma unroll
    for (int i = 0; i < 5; ++i) ss[i] += __shfl_xor(ss[i], d, 16);
  if (cg == 0) {
#pragma unroll
    for (int i = 0; i < 5; ++i) rowss[h][rg * 5 + i] = ss[i];
  }
  __syncthreads();

#pragma unroll
  for (int i = 0; i < 5; ++i) {
    int lrow = rg * 5 + i;
    float scale = rsqrtf(fmaxf(rowss[0][lrow] + rowss[1][lrow], 1e-12f));
    size_t n = (size_t)(row0 + lrow);
    float* op = out + n * 256 + h * 128 + cg * 8;
    float4 o0, o1;
    o0.x = acc[i][0] * scale; o0.y = acc[i][1] * scale;
    o0.z = acc[i][2] * scale; o0.w = acc[i][3] * scale;
    o1.x = acc[i][4] * scale; o1.y = acc[i][5] * scale;
    o1.z = acc[i][6] * scale; o1.w = acc[i][7] * scale;
    *(float4*)op = o0;
    *(float4*)(op + 4) = o1;
  }
}

extern "C" void kernel_launch(void* const* d_in, const int* in_sizes, int n_in,
                              void* d_out, int out_size, void* d_ws, size_t ws_size,
                              hipStream_t stream) {
  const float* x      = (const float*)d_in[0];
  const float* Wself  = (const float*)d_in[1];
  const float* Wneigh = (const float*)d_in[2];
  const float* bias   = (const float*)d_in[3];
  const int*   src    = (const int*)d_in[4];   // jnp.int64 degrades to int32 (x64 off)
  const int*   dst    = (const int*)d_in[5];
  float* out = (float*)d_out;

  char* p = (char*)d_ws;
  int*    cursor = (int*)p;                    // 200,000 B
  int*    bucket = (int*)(p + 200704);         // 12,800,000 B
  __half* xh     = (__half*)(p + 13001728);    // 12,800,000 B (end ~25.8 MB)

  hipMemsetAsync(cursor, 0, 200000, stream);
  pack_x      <<<(N_NODES * F_DIM) / 1024, 256, 0, stream>>>(x, xh);
  fill_bucket <<<E_EDGES / 256, 256, 0, stream>>>(src, dst, cursor, bucket);
  fused_kernel<<<N_NODES / NPB, 256, 0, stream>>>(x, xh, cursor, bucket,
                                                  Wself, Wneigh, bias, out);
}

// Round 9
// 168.920 us; speedup vs baseline: 3.7782x; 1.0866x over previous
//
#include <hip/hip_runtime.h>
#include <hip/hip_fp16.h>
#include <math.h>

#define N_NODES 50000
#define F_DIM   128
#define E_EDGES 800000
#define NPB     32      // nodes per fused block -> 1563 blocks (last block 16 rows)
#define NBLK    1563
#define CAP     64      // bucket capacity per node (Poisson(16): P(deg>64) ~ 0)
#define APAD    132     // padded row stride (floats)
#define NMASKW  400000  // 12.8M elements / 32 bits

// ---------------- JAX threefry (partitionable path, o0^o1) — verified r2 ----------------
__device__ __forceinline__ unsigned rotl32(unsigned x, int d) {
  return (x << d) | (x >> (32 - d));
}

__device__ __forceinline__ void tf2x32(unsigned k0, unsigned k1,
                                       unsigned c0, unsigned c1,
                                       unsigned &o0, unsigned &o1) {
  unsigned ks2 = k0 ^ k1 ^ 0x1BD11BDAu;
  unsigned x0 = c0 + k0, x1 = c1 + k1;
#define TF_R(a) { x0 += x1; x1 = rotl32(x1, a); x1 ^= x0; }
  TF_R(13) TF_R(15) TF_R(26) TF_R(6)   x0 += k1;  x1 += ks2 + 1u;
  TF_R(17) TF_R(29) TF_R(16) TF_R(24)  x0 += ks2; x1 += k0 + 2u;
  TF_R(13) TF_R(15) TF_R(26) TF_R(6)   x0 += k0;  x1 += k1 + 3u;
  TF_R(17) TF_R(29) TF_R(16) TF_R(24)  x0 += k1;  x1 += ks2 + 4u;
  TF_R(13) TF_R(15) TF_R(26) TF_R(6)   x0 += ks2; x1 += k0 + 5u;
#undef TF_R
  o0 = x0; o1 = x1;
}

__device__ __forceinline__ bool keep_elem(unsigned j) {
  unsigned o0, o1;
  tf2x32(0u, 42u, 0u, j, o0, o1);
  unsigned bits = o0 ^ o1;
  float uf = __uint_as_float((bits >> 9) | 0x3f800000u) - 1.0f;
  return uf < 0.7f;
}

// ---------------- pack x -> fp16 (halves gather traffic) ----------------
__global__ __launch_bounds__(256) void pack_x(const float* __restrict__ x,
                                              __half* __restrict__ xh) {
  int i = blockIdx.x * 256 + threadIdx.x;        // one float4 -> one half4 (8B)
  float4 v = ((const float4*)x)[i];              // grid covers 1.6M float4 exactly
  __half2 h01 = __floats2half2_rn(v.x, v.y);
  __half2 h23 = __floats2half2_rn(v.z, v.w);
  float2 o;
  o.x = __uint_as_float(*(const unsigned*)&h01);
  o.y = __uint_as_float(*(const unsigned*)&h23);
  ((float2*)xh)[i] = o;
}

// ------- bucket build + dropout bitmask (threefry hides under atomic latency) -------
__global__ __launch_bounds__(256) void fill_bucket(const int* __restrict__ src,
                                                   const int* __restrict__ dst,
                                                   int* __restrict__ cursor,
                                                   int* __restrict__ bucket,
                                                   unsigned* __restrict__ mask) {
  int e = blockIdx.x * 256 + threadIdx.x;   // grid covers exactly E_EDGES
  int d = dst[e];
  int pos = atomicAdd(&cursor[d], 1);
  if (pos < CAP) bucket[d * CAP + pos] = src[e];
  if (e < NMASKW) {                         // one 32-bit mask word per thread
    unsigned base = (unsigned)e * 32u;
    unsigned w = 0;
#pragma unroll 4
    for (int b = 0; b < 32; ++b) w |= (keep_elem(base + b) ? 1u : 0u) << b;
    mask[e] = w;
  }
}

// -------- fused: fp16 gather-mean (8-edge ILP) + dual GEMM + mask epilogue --------
// Gather: 8 groups of 32 lanes; group g owns nodes g, g+8, g+16, g+24. Edge lists staged
//   as ints inside A[1][ln] (consumed before the float row overwrites it).
// GEMM: h=t>>7 (0:self/A[0], 1:neigh/A[1]), rg=(t>>4)&7 -> 4 rows, cg=t&15 -> 8 cols.
__global__ __launch_bounds__(256) void fused_kernel(
    const float* __restrict__ x, const __half* __restrict__ xh,
    const int* __restrict__ cursor, const int* __restrict__ bucket,
    const float* __restrict__ Wself, const float* __restrict__ Wneigh,
    const float* __restrict__ bias, const unsigned* __restrict__ mask,
    float* __restrict__ out) {
  __shared__ __align__(16) float A[2][NPB][APAD];   // 33.8 KB -> 4 blocks/CU
  __shared__ float rowss[2][NPB];
  __shared__ int   degs[NPB];
  __shared__ float invd[NPB];

  const int t = threadIdx.x;
  const int row0 = blockIdx.x * NPB;

  // ---- stage x rows (1024 float4 = 4 exact rounds; clamp rows for last block) ----
#pragma unroll
  for (int k = 0; k < 4; ++k) {
    int q = k * 256 + t;
    int row = q >> 5, f4 = q & 31;
    int grow = row0 + row;
    if (grow > N_NODES - 1) grow = N_NODES - 1;
    ((float4*)A[0][row])[f4] = ((const float4*)(x + (size_t)grow * F_DIM))[f4];
  }
  // ---- stage edge lists into A[1] rows as ints (512 int4 = 2 exact rounds) ----
  {
    const int4* b4 = (const int4*)(bucket + (size_t)row0 * CAP);
#pragma unroll
    for (int k = 0; k < 2; ++k) {
      int s = k * 256 + t;                   // int4 slot: ln = s>>4, slot = s&15
      int ln = s >> 4;
      if (row0 + ln < N_NODES)
        ((int4*)A[1][ln])[s & 15] = b4[s];
    }
  }
  if (t < NPB) {
    int d = (row0 + t < N_NODES) ? cursor[row0 + t] : 0;
    d = d < CAP ? d : CAP;
    degs[t] = d;
    invd[t] = 1.0f / (float)(d > 1 ? d : 1);
  }
  __syncthreads();

  // ---- gather: fp16 rows, 8 independent loads in flight ----
  {
    const int g = t >> 5, li = t & 31;
    const float2* xr = (const float2*)xh;    // 8B granules; row stride = 32
#define ACCH(u) { __half2 h01 = *(const __half2*)&(u).x; \
                  __half2 h23 = *(const __half2*)&(u).y; \
                  float2 f01 = __half22float2(h01); \
                  float2 f23 = __half22float2(h23); \
                  ax += f01.x; ay += f01.y; az += f23.x; aw += f23.y; }
    for (int ln = g; ln < NPB; ln += 8) {
      const int deg = degs[ln];
      const int* ep = (const int*)A[1][ln];  // this node's staged edge list
      float ax = 0.f, ay = 0.f, az = 0.f, aw = 0.f;
      int j = 0;
      for (; j + 8 <= deg; j += 8) {
        int4 e0 = ((const int4*)ep)[(j >> 2) + 0];
        int4 e1 = ((const int4*)ep)[(j >> 2) + 1];
        float2 u0 = xr[(size_t)e0.x * 32 + li];
        float2 u1 = xr[(size_t)e0.y * 32 + li];
        float2 u2 = xr[(size_t)e0.z * 32 + li];
        float2 u3 = xr[(size_t)e0.w * 32 + li];
        float2 u4 = xr[(size_t)e1.x * 32 + li];
        float2 u5 = xr[(size_t)e1.y * 32 + li];
        float2 u6 = xr[(size_t)e1.z * 32 + li];
        float2 u7 = xr[(size_t)e1.w * 32 + li];
        ACCH(u0) ACCH(u1) ACCH(u2) ACCH(u3)
        ACCH(u4) ACCH(u5) ACCH(u6) ACCH(u7)
      }
      if (j + 4 <= deg) {
        int4 e0 = ((const int4*)ep)[j >> 2];
        float2 u0 = xr[(size_t)e0.x * 32 + li];
        float2 u1 = xr[(size_t)e0.y * 32 + li];
        float2 u2 = xr[(size_t)e0.z * 32 + li];
        float2 u3 = xr[(size_t)e0.w * 32 + li];
        ACCH(u0) ACCH(u1) ACCH(u2) ACCH(u3)
        j += 4;
      }
      for (; j < deg; ++j) {
        int e0 = ep[j];
        float2 u0 = xr[(size_t)e0 * 32 + li];
        ACCH(u0)
      }
      float s = invd[ln];
      float4 r; r.x = ax * s; r.y = ay * s; r.z = az * s; r.w = aw * s;
      ((float4*)A[1][ln])[li] = r;           // overwrites own (consumed) edge list
    }
#undef ACCH
  }
  __syncthreads();

  // ---- GEMM phase ----
  const int h = t >> 7, rg = (t >> 4) & 7, cg = t & 15;
  const float* W = h ? Wneigh : Wself;

  float acc[4][8];
#pragma unroll
  for (int i = 0; i < 4; ++i)
#pragma unroll
    for (int c = 0; c < 8; ++c) acc[i][c] = 0.0f;

  for (int kc = 0; kc < 16; ++kc) {          // 8 k-values per chunk
    float4 w0[8], w1[8];
#pragma unroll
    for (int f = 0; f < 8; ++f) {
      const float* wr = W + (size_t)(kc * 8 + f) * 128 + cg * 8;
      w0[f] = *(const float4*)wr;
      w1[f] = *(const float4*)(wr + 4);
    }
#pragma unroll
    for (int i = 0; i < 4; ++i) {
      const float4* Ap = (const float4*)A[h][rg * 4 + i];
      float4 a0 = Ap[kc * 2 + 0];
      float4 a1 = Ap[kc * 2 + 1];
#define FMA8(av, f) \
      acc[i][0] = fmaf(av, w0[f].x, acc[i][0]); \
      acc[i][1] = fmaf(av, w0[f].y, acc[i][1]); \
      acc[i][2] = fmaf(av, w0[f].z, acc[i][2]); \
      acc[i][3] = fmaf(av, w0[f].w, acc[i][3]); \
      acc[i][4] = fmaf(av, w1[f].x, acc[i][4]); \
      acc[i][5] = fmaf(av, w1[f].y, acc[i][5]); \
      acc[i][6] = fmaf(av, w1[f].z, acc[i][6]); \
      acc[i][7] = fmaf(av, w1[f].w, acc[i][7]);
      FMA8(a0.x, 0) FMA8(a0.y, 1) FMA8(a0.z, 2) FMA8(a0.w, 3)
      FMA8(a1.x, 4) FMA8(a1.y, 5) FMA8(a1.z, 6) FMA8(a1.w, 7)
#undef FMA8
    }
  }

  // ---- epilogue: +bias, ELU, dropout (precomputed mask), l2norm, store ----
  float4 b0 = ((const float4*)bias)[h * 32 + cg * 2];
  float4 b1 = ((const float4*)bias)[h * 32 + cg * 2 + 1];
  float bb[8] = {b0.x, b0.y, b0.z, b0.w, b1.x, b1.y, b1.z, b1.w};

  float ss[4];
#pragma unroll
  for (int i = 0; i < 4; ++i) {
    unsigned n = row0 + rg * 4 + i;
    unsigned mw = (n < N_NODES) ? mask[n * 8u + (unsigned)h * 4u + (cg >> 2)] : 0u;
    unsigned sh = (cg & 3) * 8;
    ss[i] = 0.0f;
#pragma unroll
    for (int c = 0; c < 8; ++c) {
      float val = acc[i][c] + bb[c];
      val = (val > 0.0f) ? val : expm1f(val);
      val = ((mw >> (sh + c)) & 1u) ? val * (1.0f / 0.7f) : 0.0f;
      acc[i][c] = val;
      ss[i] = fmaf(val, val, ss[i]);
    }
  }
#pragma unroll
  for (int d = 1; d < 16; d <<= 1)
#pragma unroll
    for (int i = 0; i < 4; ++i) ss[i] += __shfl_xor(ss[i], d, 16);
  if (cg == 0) {
#pragma unroll
    for (int i = 0; i < 4; ++i) rowss[h][rg * 4 + i] = ss[i];
  }
  __syncthreads();

#pragma unroll
  for (int i = 0; i < 4; ++i) {
    int lrow = rg * 4 + i;
    size_t n = (size_t)(row0 + lrow);
    if (n < N_NODES) {
      float scale = rsqrtf(fmaxf(rowss[0][lrow] + rowss[1][lrow], 1e-12f));
      float* op = out + n * 256 + h * 128 + cg * 8;
      float4 o0, o1;
      o0.x = acc[i][0] * scale; o0.y = acc[i][1] * scale;
      o0.z = acc[i][2] * scale; o0.w = acc[i][3] * scale;
      o1.x = acc[i][4] * scale; o1.y = acc[i][5] * scale;
      o1.z = acc[i][6] * scale; o1.w = acc[i][7] * scale;
      *(float4*)op = o0;
      *(float4*)(op + 4) = o1;
    }
  }
}

extern "C" void kernel_launch(void* const* d_in, const int* in_sizes, int n_in,
                              void* d_out, int out_size, void* d_ws, size_t ws_size,
                              hipStream_t stream) {
  const float* x      = (const float*)d_in[0];
  const float* Wself  = (const float*)d_in[1];
  const float* Wneigh = (const float*)d_in[2];
  const float* bias   = (const float*)d_in[3];
  const int*   src    = (const int*)d_in[4];   // jnp.int64 degrades to int32 (x64 off)
  const int*   dst    = (const int*)d_in[5];
  float* out = (float*)d_out;

  char* p = (char*)d_ws;
  int*      cursor = (int*)p;                    // 200,000 B (pad 200,704)
  int*      bucket = (int*)(p + 200704);         // 12,800,000 B (pad to 13,001,728)
  __half*   xh     = (__half*)(p + 13001728);    // 12,800,000 B
  unsigned* mask   = (unsigned*)(p + 25801728);  // 1,600,000 B (end ~27.4 MB)

  hipMemsetAsync(cursor, 0, 200000, stream);
  pack_x      <<<(N_NODES * F_DIM) / 1024, 256, 0, stream>>>(x, xh);
  fill_bucket <<<E_EDGES / 256, 256, 0, stream>>>(src, dst, cursor, bucket, mask);
  fused_kernel<<<NBLK, 256, 0, stream>>>(x, xh, cursor, bucket,
                                         Wself, Wneigh, bias, mask, out);
}

// Round 10
// 160.889 us; speedup vs baseline: 3.9668x; 1.0499x over previous
//
#include <hip/hip_runtime.h>
#include <hip/hip_fp16.h>
#include <math.h>

#define N_NODES 50000
#define F_DIM   128
#define E_EDGES 800000
#define NPB     32      // nodes per fused block -> 1563 blocks (last block 16 rows)
#define NBLK    1563
#define CAP     64      // bucket capacity per node (max observed deg <= 64, verified passing)
#define APAD    132     // padded row stride (floats)
#define NMASKW  400000  // 12.8M elements / 32 bits
#define FILL_BLOCKS (E_EDGES / 256)            // 3125
#define PACK_BLOCKS ((N_NODES * F_DIM) / 1024) // 6250

// ---------------- JAX threefry (partitionable path, o0^o1) — verified r2 ----------------
__device__ __forceinline__ unsigned rotl32(unsigned x, int d) {
  return (x << d) | (x >> (32 - d));
}

__device__ __forceinline__ void tf2x32(unsigned k0, unsigned k1,
                                       unsigned c0, unsigned c1,
                                       unsigned &o0, unsigned &o1) {
  unsigned ks2 = k0 ^ k1 ^ 0x1BD11BDAu;
  unsigned x0 = c0 + k0, x1 = c1 + k1;
#define TF_R(a) { x0 += x1; x1 = rotl32(x1, a); x1 ^= x0; }
  TF_R(13) TF_R(15) TF_R(26) TF_R(6)   x0 += k1;  x1 += ks2 + 1u;
  TF_R(17) TF_R(29) TF_R(16) TF_R(24)  x0 += ks2; x1 += k0 + 2u;
  TF_R(13) TF_R(15) TF_R(26) TF_R(6)   x0 += k0;  x1 += k1 + 3u;
  TF_R(17) TF_R(29) TF_R(16) TF_R(24)  x0 += k1;  x1 += ks2 + 4u;
  TF_R(13) TF_R(15) TF_R(26) TF_R(6)   x0 += ks2; x1 += k0 + 5u;
#undef TF_R
  o0 = x0; o1 = x1;
}

__device__ __forceinline__ bool keep_elem(unsigned j) {
  unsigned o0, o1;
  tf2x32(0u, 42u, 0u, j, o0, o1);
  unsigned bits = o0 ^ o1;
  float uf = __uint_as_float((bits >> 9) | 0x3f800000u) - 1.0f;
  return uf < 0.7f;
}

// ------- prep: bucket+mask (blocks 0..3124) overlapped with fp16 pack (3125..9374) -------
__global__ __launch_bounds__(256) void prep(const float* __restrict__ x,
                                            __half* __restrict__ xh,
                                            const int* __restrict__ src,
                                            const int* __restrict__ dst,
                                            int* __restrict__ cursor,
                                            int* __restrict__ bucket,
                                            unsigned* __restrict__ mask) {
  int b = blockIdx.x;
  if (b < FILL_BLOCKS) {
    int e = b * 256 + threadIdx.x;
    int d = dst[e];
    int pos = atomicAdd(&cursor[d], 1);
    if (pos < CAP) bucket[d * CAP + pos] = src[e];
    if (e < NMASKW) {                       // threefry hides under atomic latency
      unsigned base = (unsigned)e * 32u;
      unsigned w = 0;
#pragma unroll 4
      for (int bb = 0; bb < 32; ++bb) w |= (keep_elem(base + bb) ? 1u : 0u) << bb;
      mask[e] = w;
    }
  } else {
    int i = (b - FILL_BLOCKS) * 256 + threadIdx.x;   // one float4 -> 8B half4
    float4 v = ((const float4*)x)[i];
    __half2 h01 = __floats2half2_rn(v.x, v.y);
    __half2 h23 = __floats2half2_rn(v.z, v.w);
    float2 o;
    o.x = __uint_as_float(*(const unsigned*)&h01);
    o.y = __uint_as_float(*(const unsigned*)&h23);
    ((float2*)xh)[i] = o;
  }
}

// -------- fused: fp16 quad-node gather-mean + dual GEMM + mask epilogue --------
// Gather: 8 groups of 32 lanes; group g owns nodes {g, g+8, g+16, g+24} processed in the
//   SAME round -> 16 independent 8B loads in flight; edge lists sanitized at staging
//   (slots >= deg hold 0) so loads are unconditional; adds guarded by uniform predicates.
// GEMM: h=t>>7 (0:self/A[0], 1:neigh/A[1]), rg=(t>>4)&7 -> 4 rows, cg=t&15 -> 8 cols.
__global__ __launch_bounds__(256) void fused_kernel(
    const float* __restrict__ x, const __half* __restrict__ xh,
    const int* __restrict__ cursor, const int* __restrict__ bucket,
    const float* __restrict__ Wself, const float* __restrict__ Wneigh,
    const float* __restrict__ bias, const unsigned* __restrict__ mask,
    float* __restrict__ out) {
  __shared__ __align__(16) float A[2][NPB][APAD];   // 33.8 KB -> 4 blocks/CU
  __shared__ float rowss[2][NPB];
  __shared__ int   degs[NPB];
  __shared__ float invd[NPB];

  const int t = threadIdx.x;
  const int row0 = blockIdx.x * NPB;

  // ---- phase A: stage x rows (1024 float4) + degrees ----
#pragma unroll
  for (int k = 0; k < 4; ++k) {
    int q = k * 256 + t;
    int row = q >> 5, f4 = q & 31;
    int grow = row0 + row;
    if (grow > N_NODES - 1) grow = N_NODES - 1;
    ((float4*)A[0][row])[f4] = ((const float4*)(x + (size_t)grow * F_DIM))[f4];
  }
  if (t < NPB) {
    int d = (row0 + t < N_NODES) ? cursor[row0 + t] : 0;
    d = d < CAP ? d : CAP;
    degs[t] = d;
    invd[t] = 1.0f / (float)(d > 1 ? d : 1);
  }
  __syncthreads();

  // ---- phase B: stage edge lists, sanitized (slot >= deg -> index 0) ----
  {
    const int4* b4 = (const int4*)(bucket + (size_t)row0 * CAP);
#pragma unroll
    for (int k = 0; k < 2; ++k) {
      int s = k * 256 + t;                   // 512 int4 slots; ln = s>>4
      int ln = s >> 4;
      int si = (s & 15) * 4;
      int dg = degs[ln];
      int4 v = b4[s];                        // stays within d_ws (bucket+pad)
      v.x = (si + 0 < dg) ? v.x : 0;
      v.y = (si + 1 < dg) ? v.y : 0;
      v.z = (si + 2 < dg) ? v.z : 0;
      v.w = (si + 3 < dg) ? v.w : 0;
      ((int4*)A[1][ln])[s & 15] = v;
    }
  }
  __syncthreads();

  // ---- gather: 4 nodes per group per round, 16 loads in flight ----
  {
    const int g = t >> 5, li = t & 31;
    const float2* xr = (const float2*)xh;    // 8B granules; row stride = 32
    const int n0 = g, n1 = g + 8, n2 = g + 16, n3 = g + 24;
    const int d0 = degs[n0], d1 = degs[n1], d2 = degs[n2], d3 = degs[n3];
    const int4* p0 = (const int4*)A[1][n0];
    const int4* p1 = (const int4*)A[1][n1];
    const int4* p2 = (const int4*)A[1][n2];
    const int4* p3 = (const int4*)A[1][n3];
    float4 s0 = {0,0,0,0}, s1 = {0,0,0,0}, s2 = {0,0,0,0}, s3 = {0,0,0,0};
#define ACCH(s, u) { __half2 h01 = *(const __half2*)&(u).x; \
                     __half2 h23 = *(const __half2*)&(u).y; \
                     float2 f01 = __half22float2(h01); \
                     float2 f23 = __half22float2(h23); \
                     (s).x += f01.x; (s).y += f01.y; (s).z += f23.x; (s).w += f23.y; }
    int jmax = max(max(d0, d1), max(d2, d3));
    for (int j = 0; j < jmax; j += 4) {
      int4 e0 = p0[j >> 2], e1 = p1[j >> 2], e2 = p2[j >> 2], e3 = p3[j >> 2];
      float2 u00 = xr[(size_t)e0.x * 32 + li], u01 = xr[(size_t)e0.y * 32 + li];
      float2 u02 = xr[(size_t)e0.z * 32 + li], u03 = xr[(size_t)e0.w * 32 + li];
      float2 u10 = xr[(size_t)e1.x * 32 + li], u11 = xr[(size_t)e1.y * 32 + li];
      float2 u12 = xr[(size_t)e1.z * 32 + li], u13 = xr[(size_t)e1.w * 32 + li];
      float2 u20 = xr[(size_t)e2.x * 32 + li], u21 = xr[(size_t)e2.y * 32 + li];
      float2 u22 = xr[(size_t)e2.z * 32 + li], u23 = xr[(size_t)e2.w * 32 + li];
      float2 u30 = xr[(size_t)e3.x * 32 + li], u31 = xr[(size_t)e3.y * 32 + li];
      float2 u32 = xr[(size_t)e3.z * 32 + li], u33 = xr[(size_t)e3.w * 32 + li];
      if (j < d0) { ACCH(s0, u00)
        if (j + 1 < d0) ACCH(s0, u01)
        if (j + 2 < d0) ACCH(s0, u02)
        if (j + 3 < d0) ACCH(s0, u03) }
      if (j < d1) { ACCH(s1, u10)
        if (j + 1 < d1) ACCH(s1, u11)
        if (j + 2 < d1) ACCH(s1, u12)
        if (j + 3 < d1) ACCH(s1, u13) }
      if (j < d2) { ACCH(s2, u20)
        if (j + 1 < d2) ACCH(s2, u21)
        if (j + 2 < d2) ACCH(s2, u22)
        if (j + 3 < d2) ACCH(s2, u23) }
      if (j < d3) { ACCH(s3, u30)
        if (j + 1 < d3) ACCH(s3, u31)
        if (j + 2 < d3) ACCH(s3, u32)
        if (j + 3 < d3) ACCH(s3, u33) }
    }
#undef ACCH
    __syncthreads();                          // edge lists fully consumed block-wide
    float iv;
    iv = invd[n0]; s0.x *= iv; s0.y *= iv; s0.z *= iv; s0.w *= iv;
    iv = invd[n1]; s1.x *= iv; s1.y *= iv; s1.z *= iv; s1.w *= iv;
    iv = invd[n2]; s2.x *= iv; s2.y *= iv; s2.z *= iv; s2.w *= iv;
    iv = invd[n3]; s3.x *= iv; s3.y *= iv; s3.z *= iv; s3.w *= iv;
    ((float4*)A[1][n0])[li] = s0;
    ((float4*)A[1][n1])[li] = s1;
    ((float4*)A[1][n2])[li] = s2;
    ((float4*)A[1][n3])[li] = s3;
  }
  __syncthreads();

  // ---- GEMM phase ----
  const int h = t >> 7, rg = (t >> 4) & 7, cg = t & 15;
  const float* W = h ? Wneigh : Wself;

  float acc[4][8];
#pragma unroll
  for (int i = 0; i < 4; ++i)
#pragma unroll
    for (int c = 0; c < 8; ++c) acc[i][c] = 0.0f;

  for (int kc = 0; kc < 16; ++kc) {          // 8 k-values per chunk
    float4 w0[8], w1[8];
#pragma unroll
    for (int f = 0; f < 8; ++f) {
      const float* wr = W + (size_t)(kc * 8 + f) * 128 + cg * 8;
      w0[f] = *(const float4*)wr;
      w1[f] = *(const float4*)(wr + 4);
    }
#pragma unroll
    for (int i = 0; i < 4; ++i) {
      const float4* Ap = (const float4*)A[h][rg * 4 + i];
      float4 a0 = Ap[kc * 2 + 0];
      float4 a1 = Ap[kc * 2 + 1];
#define FMA8(av, f) \
      acc[i][0] = fmaf(av, w0[f].x, acc[i][0]); \
      acc[i][1] = fmaf(av, w0[f].y, acc[i][1]); \
      acc[i][2] = fmaf(av, w0[f].z, acc[i][2]); \
      acc[i][3] = fmaf(av, w0[f].w, acc[i][3]); \
      acc[i][4] = fmaf(av, w1[f].x, acc[i][4]); \
      acc[i][5] = fmaf(av, w1[f].y, acc[i][5]); \
      acc[i][6] = fmaf(av, w1[f].z, acc[i][6]); \
      acc[i][7] = fmaf(av, w1[f].w, acc[i][7]);
      FMA8(a0.x, 0) FMA8(a0.y, 1) FMA8(a0.z, 2) FMA8(a0.w, 3)
      FMA8(a1.x, 4) FMA8(a1.y, 5) FMA8(a1.z, 6) FMA8(a1.w, 7)
#undef FMA8
    }
  }

  // ---- epilogue: +bias, ELU, dropout (precomputed mask), l2norm, store ----
  float4 b0 = ((const float4*)bias)[h * 32 + cg * 2];
  float4 b1 = ((const float4*)bias)[h * 32 + cg * 2 + 1];
  float bb[8] = {b0.x, b0.y, b0.z, b0.w, b1.x, b1.y, b1.z, b1.w};

  float ss[4];
#pragma unroll
  for (int i = 0; i < 4; ++i) {
    unsigned n = row0 + rg * 4 + i;
    unsigned mw = (n < N_NODES) ? mask[n * 8u + (unsigned)h * 4u + (cg >> 2)] : 0u;
    unsigned sh = (cg & 3) * 8;
    ss[i] = 0.0f;
#pragma unroll
    for (int c = 0; c < 8; ++c) {
      float val = acc[i][c] + bb[c];
      val = (val > 0.0f) ? val : expm1f(val);
      val = ((mw >> (sh + c)) & 1u) ? val * (1.0f / 0.7f) : 0.0f;
      acc[i][c] = val;
      ss[i] = fmaf(val, val, ss[i]);
    }
  }
#pragma unroll
  for (int d = 1; d < 16; d <<= 1)
#pragma unroll
    for (int i = 0; i < 4; ++i) ss[i] += __shfl_xor(ss[i], d, 16);
  if (cg == 0) {
#pragma unroll
    for (int i = 0; i < 4; ++i) rowss[h][rg * 4 + i] = ss[i];
  }
  __syncthreads();

#pragma unroll
  for (int i = 0; i < 4; ++i) {
    int lrow = rg * 4 + i;
    size_t n = (size_t)(row0 + lrow);
    if (n < N_NODES) {
      float scale = rsqrtf(fmaxf(rowss[0][lrow] + rowss[1][lrow], 1e-12f));
      float* op = out + n * 256 + h * 128 + cg * 8;
      float4 o0, o1;
      o0.x = acc[i][0] * scale; o0.y = acc[i][1] * scale;
      o0.z = acc[i][2] * scale; o0.w = acc[i][3] * scale;
      o1.x = acc[i][4] * scale; o1.y = acc[i][5] * scale;
      o1.z = acc[i][6] * scale; o1.w = acc[i][7] * scale;
      *(float4*)op = o0;
      *(float4*)(op + 4) = o1;
    }
  }
}

extern "C" void kernel_launch(void* const* d_in, const int* in_sizes, int n_in,
                              void* d_out, int out_size, void* d_ws, size_t ws_size,
                              hipStream_t stream) {
  const float* x      = (const float*)d_in[0];
  const float* Wself  = (const float*)d_in[1];
  const float* Wneigh = (const float*)d_in[2];
  const float* bias   = (const float*)d_in[3];
  const int*   src    = (const int*)d_in[4];   // jnp.int64 degrades to int32 (x64 off)
  const int*   dst    = (const int*)d_in[5];
  float* out = (float*)d_out;

  char* p = (char*)d_ws;
  int*      cursor = (int*)p;                    // 200,000 B (pad 200,704)
  int*      bucket = (int*)(p + 200704);         // 12,800,000 B (pad to 13,001,728)
  __half*   xh     = (__half*)(p + 13001728);    // 12,800,000 B
  unsigned* mask   = (unsigned*)(p + 25801728);  // 1,600,000 B (end ~27.4 MB)

  hipMemsetAsync(cursor, 0, 200000, stream);
  prep        <<<FILL_BLOCKS + PACK_BLOCKS, 256, 0, stream>>>(x, xh, src, dst,
                                                              cursor, bucket, mask);
  fused_kernel<<<NBLK, 256, 0, stream>>>(x, xh, cursor, bucket,
                                         Wself, Wneigh, bias, mask, out);
}